// Round 11
// baseline (144.321 us; speedup 1.0000x reference)
//
#include <hip/hip_runtime.h>
#include <cstdint>

#define NB 8
#define NC 128
#define NPIX 4096
#define NGROUP 8
#define CPG 16
#define EPS_GN 1e-5f
// SCALE * log2(e): softmax done in exp2 domain
#define QSCALE 0.12751879523604132f
#define NSPLIT 2
#define JTILES (NPIX / 64 / NSPLIT)

typedef __attribute__((ext_vector_type(8))) short short8;
typedef __attribute__((ext_vector_type(16))) float f32x16;

typedef __attribute__((address_space(1))) const void gvoid_t;
typedef __attribute__((address_space(3))) void svoid_t;

// pack two f32 -> 2x bf16 (RNE) in one instruction (no builtin on gfx950)
__device__ __forceinline__ unsigned packbf(float lo, float hi) {
  unsigned r;
  asm("v_cvt_pk_bf16_f32 %0, %1, %2" : "=v"(r) : "v"(lo), "v"(hi));
  return r;
}
__device__ __forceinline__ ushort bf16of(float v) {
  return (ushort)(packbf(v, v) & 0xffffu);
}
__device__ __forceinline__ float bfl(unsigned w) {   // low bf16 -> f32
  return __builtin_bit_cast(float, w << 16);
}
__device__ __forceinline__ float bfh(unsigned w) {   // high bf16 -> f32
  return __builtin_bit_cast(float, w & 0xffff0000u);
}

// K-tile chunk swizzle (16 chunks of 16B per 64-row): involution via XOR
__device__ __forceinline__ int swK(int row) {
  return ((row & 7) << 1) | ((row >> 3) & 1);
}

// ---------------- K0: weight prep -> linear pre-swizzled bf16 ----------------
// wbuf tile t in {0,1,2}=w_qkv rows t*128.., t=3=w_proj. Chunk ci holds
// w[o=ci>>4][cc=(ci&15)^(o&7)], so LDS dst = linear chunk*16B (DMA-compatible).
__global__ __launch_bounds__(256) void k_wprep(const float* __restrict__ wqkv,
                                               const float* __restrict__ wproj,
                                               ushort* __restrict__ wbuf) {
  int gi = blockIdx.x * 256 + threadIdx.x;  // 0..8191
  int t = gi >> 11, ci = gi & 2047;
  int o = ci >> 4, cc = (ci & 15) ^ (o & 7);
  const float* src = (t < 3) ? (wqkv + ((size_t)(t * 128 + o) * 128 + cc * 8))
                             : (wproj + ((size_t)o * 128 + cc * 8));
  float4 a = *(const float4*)src;
  float4 b2 = *(const float4*)(src + 4);
  uint4 pk;
  pk.x = packbf(a.x, a.y);  pk.y = packbf(a.z, a.w);
  pk.z = packbf(b2.x, b2.y); pk.w = packbf(b2.z, b2.w);
  *(uint4*)&wbuf[(size_t)gi << 3] = pk;
}

// ---------------- K1: group-norm stats (mean, rstd per (b,g)) ----------------
__global__ __launch_bounds__(256) void k_gn_stats(const float* __restrict__ x,
                                                  float* __restrict__ stats) {
  int blk = blockIdx.x;
  const float4* base = (const float4*)(x + (size_t)blk * CPG * NPIX);
  float s = 0.f, ss = 0.f;
  for (int i = threadIdx.x; i < CPG * NPIX / 4; i += 256) {
    float4 v = base[i];
    s  += v.x + v.y + v.z + v.w;
    ss += v.x * v.x + v.y * v.y + v.z * v.z + v.w * v.w;
  }
#pragma unroll
  for (int off = 32; off >= 1; off >>= 1) {
    s  += __shfl_down(s, off);
    ss += __shfl_down(ss, off);
  }
  __shared__ float red[8];
  int wid = threadIdx.x >> 6;
  if ((threadIdx.x & 63) == 0) { red[wid] = s; red[4 + wid] = ss; }
  __syncthreads();
  if (threadIdx.x == 0) {
    float S  = red[0] + red[1] + red[2] + red[3];
    float SS = red[4] + red[5] + red[6] + red[7];
    float mean = S * (1.f / (CPG * NPIX));
    float var  = SS * (1.f / (CPG * NPIX)) - mean * mean;
    stats[blk * 2]     = mean;
    stats[blk * 2 + 1] = rsqrtf(var + EPS_GN);
  }
}

// ---------------- K2: QKV GEMM (MFMA bf16), W tiles DMA'd from wbuf ----------
__global__ __launch_bounds__(256) void k_qkv(const float* __restrict__ x,
                                             const float* __restrict__ stats,
                                             const float* __restrict__ gamma,
                                             const float* __restrict__ beta,
                                             const ushort* __restrict__ wbuf,
                                             const float* __restrict__ bias,
                                             ushort* __restrict__ qT,
                                             ushort* __restrict__ kT,
                                             ushort* __restrict__ vB) {
  __shared__ ushort At[128 * 128];  // W o-tile, bf16, pre-swizzled via wbuf
  __shared__ ushort Bt[128 * 128];  // normalized x tile [p][c], bf16, swizzled
  __shared__ float sArr[128], tArr[128], biasS[384];
  int b = blockIdx.x, pt = blockIdx.y;  // b fastest -> XCD affinity
  int p0 = pt * 128;
  int tid = threadIdx.x;
  if (tid < 128) {
    int g = tid >> 4;
    float mean = stats[(b * NGROUP + g) * 2];
    float rstd = stats[(b * NGROUP + g) * 2 + 1];
    float sc = rstd * gamma[tid];
    sArr[tid] = sc;
    tArr[tid] = beta[tid] - mean * sc;
  }
  for (int i = tid; i < 384; i += 256) biasS[i] = bias[i];
  __syncthreads();
  const float* xb = x + (size_t)b * NC * NPIX;
#pragma unroll
  for (int u = 0; u < 8; ++u) {
    int task = tid + u * 256;
    int p = task & 127, cc = task >> 7;
    int c0 = cc * 8;
    float v[8];
#pragma unroll
    for (int i = 0; i < 8; ++i)
      v[i] = sArr[c0 + i] * xb[(size_t)(c0 + i) * NPIX + p0 + p] + tArr[c0 + i];
    uint4 pk;
    pk.x = packbf(v[0], v[1]); pk.y = packbf(v[2], v[3]);
    pk.z = packbf(v[4], v[5]); pk.w = packbf(v[6], v[7]);
    *(uint4*)&Bt[((p << 4) + (cc ^ (p & 7))) << 3] = pk;
  }
  int lane = tid & 63, wv = tid >> 6;
  int lq = lane & 31, h = lane >> 5;

  for (int ot = 0; ot < 3; ++ot) {
    __syncthreads();  // At readers of previous iter done
#pragma unroll
    for (int u = 0; u < 8; ++u) {  // At <- wbuf tile ot, straight DMA
      int g = u * 4 + wv;          // chunk group 0..31
      __builtin_amdgcn_global_load_lds(
          (gvoid_t*)(wbuf + (((size_t)ot * 2048 + g * 64 + lane) << 3)),
          (svoid_t*)(At + (g << 9)), 16, 0, 0);
    }
    __syncthreads();  // drains vmcnt: At ready (Bt also visible on first iter)
    short8 af[8];
    int arow = wv * 32 + lq;
#pragma unroll
    for (int kk = 0; kk < 8; ++kk) {
      int ch = kk * 2 + h;
      af[kk] = *(const short8*)&At[((arow << 4) + (ch ^ (arow & 7))) << 3];
    }
#pragma unroll
    for (int np = 0; np < 2; ++np) {
      int nt0 = np * 2, nt1 = np * 2 + 1;
      int br0 = nt0 * 32 + lq, br1 = nt1 * 32 + lq;
      f32x16 a0, a1;
#pragma unroll
      for (int r = 0; r < 16; ++r) { a0[r] = 0.f; a1[r] = 0.f; }
      __builtin_amdgcn_s_setprio(1);
#pragma unroll
      for (int kk = 0; kk < 8; ++kk) {
        int ch = kk * 2 + h;
        short8 h0 = *(const short8*)&Bt[((br0 << 4) + (ch ^ (br0 & 7))) << 3];
        short8 h1 = *(const short8*)&Bt[((br1 << 4) + (ch ^ (br1 & 7))) << 3];
        a0 = __builtin_amdgcn_mfma_f32_32x32x16_bf16(af[kk], h0, a0, 0, 0, 0);
        a1 = __builtin_amdgcn_mfma_f32_32x32x16_bf16(af[kk], h1, a1, 0, 0, 0);
      }
      __builtin_amdgcn_s_setprio(0);
#pragma unroll
      for (int half = 0; half < 2; ++half) {
        f32x16& acc = half ? a1 : a0;
        int pg = p0 + (half ? nt1 : nt0) * 32 + lq;
        if (ot < 2) {  // Q or K: transposed bf16 store [p][c]
          ushort* dst = (ot == 0) ? qT : kT;
          float sc = (ot == 0) ? QSCALE : 1.0f;
#pragma unroll
          for (int g2 = 0; g2 < 4; ++g2) {
            int orow = wv * 32 + 4 * h + 8 * g2;
            uint2 st;
            st.x = packbf((acc[g2 * 4 + 0] + biasS[ot * 128 + orow + 0]) * sc,
                          (acc[g2 * 4 + 1] + biasS[ot * 128 + orow + 1]) * sc);
            st.y = packbf((acc[g2 * 4 + 2] + biasS[ot * 128 + orow + 2]) * sc,
                          (acc[g2 * 4 + 3] + biasS[ot * 128 + orow + 3]) * sc);
            *(uint2*)&dst[(((size_t)b << 12) + pg) * 128 + orow] = st;
          }
        } else {  // V: [c][n] bf16
#pragma unroll
          for (int r = 0; r < 16; ++r) {
            int orow = wv * 32 + (r & 3) + 8 * (r >> 2) + 4 * h;
            float vv = acc[r] + biasS[256 + orow];
            vB[((size_t)(b * 128 + orow) << 12) + pg] = bf16of(vv);
          }
        }
      }
    }
  }
}

// ---------------- K3: MFMA flash attention (r10 structure, bf16 partials) ----
__device__ __forceinline__ void attn_tile(const ushort* __restrict__ cur,
                                          const short8 (&qf)[8],
                                          f32x16 (&pacc)[4],
                                          float& m_run, float& l_run,
                                          int lq, int h, int swk) {
  // ---- QK^T (swapped): D[j][q] = K-tile * Q ----
  f32x16 s0, s1;
#pragma unroll
  for (int r = 0; r < 16; ++r) { s0[r] = 0.f; s1[r] = 0.f; }
  __builtin_amdgcn_s_setprio(1);
#pragma unroll
  for (int kk = 0; kk < 8; ++kk) {
    int ch = (kk << 1) + h;
    short8 kf0 = *(const short8*)&cur[(((lq) << 4) + (ch ^ swk)) << 3];
    short8 kf1 = *(const short8*)&cur[(((32 + lq) << 4) + (ch ^ swk)) << 3];
    s0 = __builtin_amdgcn_mfma_f32_32x32x16_bf16(kf0, qf[kk], s0, 0, 0, 0);
    s1 = __builtin_amdgcn_mfma_f32_32x32x16_bf16(kf1, qf[kk], s1, 0, 0, 0);
  }
  __builtin_amdgcn_s_setprio(0);

  // ---- online softmax in exp2 domain, defer-max (THR=8) ----
  float tm[8];
#pragma unroll
  for (int r = 0; r < 8; ++r)
    tm[r] = fmaxf(fmaxf(s0[2 * r], s0[2 * r + 1]), fmaxf(s1[2 * r], s1[2 * r + 1]));
  float tmax = fmaxf(fmaxf(fmaxf(tm[0], tm[1]), fmaxf(tm[2], tm[3])),
                     fmaxf(fmaxf(tm[4], tm[5]), fmaxf(tm[6], tm[7])));
  tmax = fmaxf(tmax, __shfl_xor(tmax, 32));

  bool noresc = __all(tmax - m_run <= 8.f);  // P bounded by 2^8
  float mcur = noresc ? m_run : fmaxf(m_run, tmax);

#pragma unroll
  for (int r = 0; r < 16; ++r) { s0[r] = exp2f(s0[r] - mcur); }
#pragma unroll
  for (int r = 0; r < 16; ++r) { s1[r] = exp2f(s1[r] - mcur); }
  // tree-sum (depth 5)
  float a0 = (s0[0] + s0[1]) + (s0[2] + s0[3]);
  float a1 = (s0[4] + s0[5]) + (s0[6] + s0[7]);
  float a2 = (s0[8] + s0[9]) + (s0[10] + s0[11]);
  float a3 = (s0[12] + s0[13]) + (s0[14] + s0[15]);
  float a4 = (s1[0] + s1[1]) + (s1[2] + s1[3]);
  float a5 = (s1[4] + s1[5]) + (s1[6] + s1[7]);
  float a6 = (s1[8] + s1[9]) + (s1[10] + s1[11]);
  float a7 = (s1[12] + s1[13]) + (s1[14] + s1[15]);
  float sum = ((a0 + a1) + (a2 + a3)) + ((a4 + a5) + (a6 + a7));
  sum += __shfl_xor(sum, 32);

  if (noresc) {
    l_run += sum;
  } else {
    float alpha = exp2f(m_run - mcur);
    m_run = mcur;
    l_run = l_run * alpha + sum;
#pragma unroll
    for (int r = 0; r < 16; ++r) {
      int qr = (r & 3) + ((r >> 2) << 3) + (h << 2);
      float av = __shfl(alpha, qr);
      pacc[0][r] *= av; pacc[1][r] *= av; pacc[2][r] *= av; pacc[3][r] *= av;
    }
  }

  // ---- build PA fragments: A[q][j] for PV (P values in s0/s1) ----
  short8 pa[4];
#pragma unroll
  for (int kk = 0; kk < 4; ++kk) {
    float v0, v1, v2, v3, v4, v5, v6, v7;
    if (kk == 0)      { v0=s0[0];v1=s0[1];v2=s0[2];v3=s0[3];v4=s0[4];v5=s0[5];v6=s0[6];v7=s0[7]; }
    else if (kk == 1) { v0=s0[8];v1=s0[9];v2=s0[10];v3=s0[11];v4=s0[12];v5=s0[13];v6=s0[14];v7=s0[15]; }
    else if (kk == 2) { v0=s1[0];v1=s1[1];v2=s1[2];v3=s1[3];v4=s1[4];v5=s1[5];v6=s1[6];v7=s1[7]; }
    else              { v0=s1[8];v1=s1[9];v2=s1[10];v3=s1[11];v4=s1[12];v5=s1[13];v6=s1[14];v7=s1[15]; }
    unsigned P0a = packbf(v0, v1), P0b = packbf(v2, v3);
    unsigned P1a = packbf(v4, v5), P1b = packbf(v6, v7);
    unsigned sA = h ? P0a : P1a, sB = h ? P0b : P1b;
    unsigned rA = (unsigned)__shfl_xor((int)sA, 32);
    unsigned rB = (unsigned)__shfl_xor((int)sB, 32);
    uint4 wv;
    wv.x = h ? rA : P0a;  wv.y = h ? rB : P0b;
    wv.z = h ? P1a : rA;  wv.w = h ? P1b : rB;
    pa[kk] = __builtin_bit_cast(short8, wv);
  }

  // ---- PV: D[q][c] += P * V^T ----
  __builtin_amdgcn_s_setprio(1);
#pragma unroll
  for (int nt = 0; nt < 4; ++nt) {
    int row = (nt << 5) + lq;
#pragma unroll
    for (int kk = 0; kk < 4; ++kk) {
      int ch = (kk << 1) + h;
      short8 vf = *(const short8*)&cur[8192 + (((row << 3) + (ch ^ (lq & 7))) << 3)];
      pacc[nt] = __builtin_amdgcn_mfma_f32_32x32x16_bf16(pa[kk], vf, pacc[nt], 0, 0, 0);
    }
  }
  __builtin_amdgcn_s_setprio(0);
}

__global__ __launch_bounds__(256, 2) void k_attn(const ushort* __restrict__ qT,
                                                 const ushort* __restrict__ kT,
                                                 const ushort* __restrict__ vB,
                                                 ushort* __restrict__ attP,
                                                 float2* __restrict__ mlv) {
  __shared__ ushort lds[32768];  // 2 x (K 16KB + V 16KB)
  int tid = threadIdx.x;
  int b = blockIdx.x, qt = blockIdx.y, s = blockIdx.z;  // b fastest -> XCD aff.
  int wid = tid >> 6;
  int lane = tid & 63;
  int lq = lane & 31;
  int h = lane >> 5;
  int swk = swK(lq);  // == swK(32+lq)
  int q0 = qt * 128 + wid * 32;
  int jbase = s * (NPIX / NSPLIT);

  short8 qf[8];
  const ushort* qp = qT + (((size_t)b << 12) + q0 + lq) * 128 + h * 8;
#pragma unroll
  for (int kk = 0; kk < 8; ++kk) qf[kk] = *(const short8*)(qp + kk * 16);

  f32x16 pacc[4];
#pragma unroll
  for (int nt = 0; nt < 4; ++nt)
#pragma unroll
    for (int r = 0; r < 16; ++r) pacc[nt][r] = 0.f;
  float m_run = -1e30f, l_run = 0.f;

  // ---- loop-invariant per-lane staging pointers ----
  int id0 = wid * 64 + lane;
  int krow0 = id0 >> 4, kch0 = id0 & 15;
  int vrow0 = id0 >> 3, vch0 = id0 & 7;
  const ushort* kbase = kT + (((size_t)b << 12) + jbase + krow0) * 128 +
                        ((kch0 ^ swK(krow0)) << 3);
  const ushort* vbase = vB + ((size_t)(b * 128 + vrow0) << 12) + jbase +
                        ((vch0 ^ (vrow0 & 7)) << 3);
  int tstage = 0;

#define STAGE(SEL)                                                              \
  do {                                                                          \
    if (tstage < JTILES) {                                                      \
      ushort* dbase = lds + (SEL) * 16384;                                      \
      _Pragma("unroll") for (int u = 0; u < 4; ++u) {                           \
        __builtin_amdgcn_global_load_lds((gvoid_t*)(kbase + u * 2048),          \
            (svoid_t*)(dbase + (u * 4 + wid) * 512), 16, 0, 0);                 \
        __builtin_amdgcn_global_load_lds((gvoid_t*)(vbase + u * 131072),        \
            (svoid_t*)(dbase + 8192 + (u * 4 + wid) * 512), 16, 0, 0);          \
      }                                                                         \
      kbase += 8192;  /* 64 keys * 128 c */                                     \
      vbase += 64;    /* 64 keys */                                             \
      ++tstage;                                                                 \
    }                                                                           \
  } while (0)

  STAGE(0);  // tile 0 -> buf0
  for (int it = 0; it < JTILES / 2; ++it) {
    __syncthreads();            // buf0 DMA done; prior buf0 readers done
    STAGE(1);                   // next tile -> buf1
    attn_tile(lds, qf, pacc, m_run, l_run, lq, h, swk);
    __syncthreads();            // buf1 DMA done; buf0 readers done
    STAGE(0);                   // next tile -> buf0
    attn_tile(lds + 16384, qf, pacc, m_run, l_run, lq, h, swk);
  }
#undef STAGE

  // ---- epilogue: bf16 partial O + (m,l); combine in k_proj ----
  size_t sb = (size_t)(s * NB + b);
#pragma unroll
  for (int r = 0; r < 16; ++r) {
    int qr = (r & 3) + ((r >> 2) << 3) + (h << 2);
    size_t rowbase = (((sb << 12) + q0 + qr) << 7) + lq;
    attP[rowbase]      = bf16of(pacc[0][r]);
    attP[rowbase + 32] = bf16of(pacc[1][r]);
    attP[rowbase + 64] = bf16of(pacc[2][r]);
    attP[rowbase + 96] = bf16of(pacc[3][r]);
  }
  if (h == 0) {
    mlv[(sb << 12) + q0 + lq] = make_float2(m_run, l_run);
  }
}

// ---------------- K4: split-combine (bf16) + proj (MFMA) + residual ----------
__global__ __launch_bounds__(256) void k_proj(const float* __restrict__ x,
                                              const ushort* __restrict__ attP,
                                              const float2* __restrict__ mlv,
                                              const ushort* __restrict__ wbuf,
                                              const float* __restrict__ bias,
                                              float* __restrict__ out) {
  __shared__ ushort At[128 * 128];
  __shared__ ushort Bt[128 * 128];
  __shared__ float c0s[128], c1s[128], biasS[128];
  int b = blockIdx.x, pt = blockIdx.y;  // b fastest
  int p0 = pt * 128;
  int tid = threadIdx.x;
  int lane = tid & 63, wv = tid >> 6;
  // At <- wbuf tile 3 (w_proj), straight DMA
#pragma unroll
  for (int u = 0; u < 8; ++u) {
    int g = u * 4 + wv;
    __builtin_amdgcn_global_load_lds(
        (gvoid_t*)(wbuf + (((size_t)3 * 2048 + g * 64 + lane) << 3)),
        (svoid_t*)(At + (g << 9)), 16, 0, 0);
  }
  if (tid < 128) {
    float2 ml0 = mlv[(((size_t)b) << 12) + p0 + tid];
    float2 ml1 = mlv[(((size_t)(NB + b)) << 12) + p0 + tid];
    float M = fmaxf(ml0.x, ml1.x);
    float e0 = exp2f(ml0.x - M), e1 = exp2f(ml1.x - M);
    float inv = 1.f / (ml0.y * e0 + ml1.y * e1);
    c0s[tid] = e0 * inv;
    c1s[tid] = e1 * inv;
    biasS[tid] = bias[tid];
  }
  __syncthreads();
#pragma unroll
  for (int u = 0; u < 8; ++u) {  // Bt: combine two bf16 splits -> bf16 swizzled
    int task = tid + u * 256;
    int p = task & 127, cc = task >> 7;
    const ushort* a0p = attP + ((((size_t)b << 12) + p0 + p) << 7) + cc * 8;
    const ushort* a1p = attP + ((((size_t)(NB + b) << 12) + p0 + p) << 7) + cc * 8;
    uint4 u0 = *(const uint4*)a0p;
    uint4 u1 = *(const uint4*)a1p;
    float c0 = c0s[p], c1 = c1s[p];
    uint4 pk;
    pk.x = packbf(bfl(u0.x) * c0 + bfl(u1.x) * c1,
                  bfh(u0.x) * c0 + bfh(u1.x) * c1);
    pk.y = packbf(bfl(u0.y) * c0 + bfl(u1.y) * c1,
                  bfh(u0.y) * c0 + bfh(u1.y) * c1);
    pk.z = packbf(bfl(u0.z) * c0 + bfl(u1.z) * c1,
                  bfh(u0.z) * c0 + bfh(u1.z) * c1);
    pk.w = packbf(bfl(u0.w) * c0 + bfl(u1.w) * c1,
                  bfh(u0.w) * c0 + bfh(u1.w) * c1);
    *(uint4*)&Bt[((p << 4) + (cc ^ (p & 7))) << 3] = pk;
  }
  __syncthreads();  // drains vmcnt (At DMA) + Bt ds_writes
  int lq = lane & 31, h = lane >> 5;
  short8 af[8];
  int arow = wv * 32 + lq;
#pragma unroll
  for (int kk = 0; kk < 8; ++kk) {
    int ch = kk * 2 + h;
    af[kk] = *(const short8*)&At[((arow << 4) + (ch ^ (arow & 7))) << 3];
  }
  const float* xb = x + (size_t)b * NC * NPIX;
  float* ob = out + (size_t)b * NC * NPIX;
#pragma unroll
  for (int np = 0; np < 2; ++np) {
    int nt0 = np * 2, nt1 = np * 2 + 1;
    int br0 = nt0 * 32 + lq, br1 = nt1 * 32 + lq;
    f32x16 a0, a1;
#pragma unroll
    for (int r = 0; r < 16; ++r) { a0[r] = 0.f; a1[r] = 0.f; }
    __builtin_amdgcn_s_setprio(1);
#pragma unroll
    for (int kk = 0; kk < 8; ++kk) {
      int ch = kk * 2 + h;
      short8 h0 = *(const short8*)&Bt[((br0 << 4) + (ch ^ (br0 & 7))) << 3];
      short8 h1 = *(const short8*)&Bt[((br1 << 4) + (ch ^ (br1 & 7))) << 3];
      a0 = __builtin_amdgcn_mfma_f32_32x32x16_bf16(af[kk], h0, a0, 0, 0, 0);
      a1 = __builtin_amdgcn_mfma_f32_32x32x16_bf16(af[kk], h1, a1, 0, 0, 0);
    }
    __builtin_amdgcn_s_setprio(0);
#pragma unroll
    for (int half = 0; half < 2; ++half) {
      f32x16& acc = half ? a1 : a0;
      int pg = p0 + (half ? nt1 : nt0) * 32 + lq;
#pragma unroll
      for (int r = 0; r < 16; ++r) {
        int orow = wv * 32 + (r & 3) + 8 * (r >> 2) + 4 * h;
        size_t idx = ((size_t)orow << 12) + pg;
        ob[idx] = acc[r] + biasS[orow] + xb[idx];
      }
    }
  }
}

extern "C" void kernel_launch(void* const* d_in, const int* in_sizes, int n_in,
                              void* d_out, int out_size, void* d_ws, size_t ws_size,
                              hipStream_t stream) {
  const float* x      = (const float*)d_in[0];
  const float* gamma  = (const float*)d_in[1];
  const float* beta   = (const float*)d_in[2];
  const float* w_qkv  = (const float*)d_in[3];
  const float* b_qkv  = (const float*)d_in[4];
  const float* w_proj = (const float*)d_in[5];
  const float* b_proj = (const float*)d_in[6];
  float* out = (float*)d_out;
  char* wsb = (char*)d_ws;

  float*  stats = (float*)wsb;                          // 1 KB
  ushort* qT    = (ushort*)(wsb + 1024);                // 8 MB
  ushort* kT    = (ushort*)(wsb + 1024 + (8u << 20));   // 8 MB
  ushort* vB    = (ushort*)(wsb + 1024 + (16u << 20));  // 8 MB
  ushort* attP  = (ushort*)(wsb + 1024 + (24u << 20));  // 16 MB (2 splits bf16)
  float2* mlv   = (float2*)(wsb + 1024 + (40u << 20));  // 512 KB
  ushort* wbuf  = (ushort*)(wsb + 1024 + (41u << 20));  // 128 KB

  hipLaunchKernelGGL(k_wprep, dim3(32), dim3(256), 0, stream, w_qkv, w_proj, wbuf);
  hipLaunchKernelGGL(k_gn_stats, dim3(NB * NGROUP), dim3(256), 0, stream, x, stats);
  hipLaunchKernelGGL(k_qkv, dim3(NB, NPIX / 128), dim3(256), 0, stream,
                     x, stats, gamma, beta, wbuf, b_qkv, qT, kT, vB);
  hipLaunchKernelGGL(k_attn, dim3(NB, NPIX / 128, NSPLIT), dim3(256), 0, stream,
                     qT, kT, vB, attP, mlv);
  hipLaunchKernelGGL(k_proj, dim3(NB, NPIX / 128), dim3(256), 0, stream,
                     x, attP, mlv, wbuf, b_proj, out);
}

// Round 12
// 139.022 us; speedup vs baseline: 1.0381x; 1.0381x over previous
//
#include <hip/hip_runtime.h>
#include <cstdint>

#define NB 8
#define NC 128
#define NPIX 4096
#define NGROUP 8
#define CPG 16
#define EPS_GN 1e-5f
// SCALE * log2(e): softmax done in exp2 domain
#define QSCALE 0.12751879523604132f
#define NSPLIT 2
#define JTILES (NPIX / 64 / NSPLIT)

typedef __attribute__((ext_vector_type(8))) short short8;
typedef __attribute__((ext_vector_type(16))) float f32x16;

typedef __attribute__((address_space(1))) const void gvoid_t;
typedef __attribute__((address_space(3))) void svoid_t;

// pack two f32 -> 2x bf16 (RNE) in one instruction (no builtin on gfx950)
__device__ __forceinline__ unsigned packbf(float lo, float hi) {
  unsigned r;
  asm("v_cvt_pk_bf16_f32 %0, %1, %2" : "=v"(r) : "v"(lo), "v"(hi));
  return r;
}
__device__ __forceinline__ ushort bf16of(float v) {
  return (ushort)(packbf(v, v) & 0xffffu);
}
__device__ __forceinline__ float bfl(unsigned w) {   // low bf16 -> f32
  return __builtin_bit_cast(float, w << 16);
}
__device__ __forceinline__ float bfh(unsigned w) {   // high bf16 -> f32
  return __builtin_bit_cast(float, w & 0xffff0000u);
}

// K-tile chunk swizzle (16 chunks of 16B per 64-row): involution via XOR
__device__ __forceinline__ int swK(int row) {
  return ((row & 7) << 1) | ((row >> 3) & 1);
}

// ---------------- K1: fused prep: gn stats (blocks 0..63) + wprep (64..95) ---
__global__ __launch_bounds__(256) void k_pre(const float* __restrict__ x,
                                             float* __restrict__ stats,
                                             const float* __restrict__ wqkv,
                                             const float* __restrict__ wproj,
                                             ushort* __restrict__ wbuf) {
  int blk = blockIdx.x;
  if (blk < 64) {
    const float4* base = (const float4*)(x + (size_t)blk * CPG * NPIX);
    float s = 0.f, ss = 0.f;
    for (int i = threadIdx.x; i < CPG * NPIX / 4; i += 256) {
      float4 v = base[i];
      s  += v.x + v.y + v.z + v.w;
      ss += v.x * v.x + v.y * v.y + v.z * v.z + v.w * v.w;
    }
#pragma unroll
    for (int off = 32; off >= 1; off >>= 1) {
      s  += __shfl_down(s, off);
      ss += __shfl_down(ss, off);
    }
    __shared__ float red[8];
    int wid = threadIdx.x >> 6;
    if ((threadIdx.x & 63) == 0) { red[wid] = s; red[4 + wid] = ss; }
    __syncthreads();
    if (threadIdx.x == 0) {
      float S  = red[0] + red[1] + red[2] + red[3];
      float SS = red[4] + red[5] + red[6] + red[7];
      float mean = S * (1.f / (CPG * NPIX));
      float var  = SS * (1.f / (CPG * NPIX)) - mean * mean;
      stats[blk * 2]     = mean;
      stats[blk * 2 + 1] = rsqrtf(var + EPS_GN);
    }
  } else {
    int gi = (blk - 64) * 256 + threadIdx.x;  // 0..8191
    int t = gi >> 11, ci = gi & 2047;
    int o = ci >> 4, cc = (ci & 15) ^ (o & 7);
    const float* src = (t < 3) ? (wqkv + ((size_t)(t * 128 + o) * 128 + cc * 8))
                               : (wproj + ((size_t)o * 128 + cc * 8));
    float4 a = *(const float4*)src;
    float4 b2 = *(const float4*)(src + 4);
    uint4 pk;
    pk.x = packbf(a.x, a.y);  pk.y = packbf(a.z, a.w);
    pk.z = packbf(b2.x, b2.y); pk.w = packbf(b2.z, b2.w);
    *(uint4*)&wbuf[(size_t)gi << 3] = pk;
  }
}

// ---------------- K2: QKV GEMM (MFMA bf16), W tiles DMA'd from wbuf ----------
__global__ __launch_bounds__(256) void k_qkv(const float* __restrict__ x,
                                             const float* __restrict__ stats,
                                             const float* __restrict__ gamma,
                                             const float* __restrict__ beta,
                                             const ushort* __restrict__ wbuf,
                                             const float* __restrict__ bias,
                                             ushort* __restrict__ qT,
                                             ushort* __restrict__ kT,
                                             ushort* __restrict__ vB) {
  __shared__ ushort At[128 * 128];  // W o-tile, bf16, pre-swizzled via wbuf
  __shared__ ushort Bt[128 * 128];  // normalized x tile [p][c], bf16, swizzled
  __shared__ float sArr[128], tArr[128], biasS[384];
  int b = blockIdx.x, pt = blockIdx.y;  // b fastest -> XCD affinity
  int p0 = pt * 128;
  int tid = threadIdx.x;
  if (tid < 128) {
    int g = tid >> 4;
    float mean = stats[(b * NGROUP + g) * 2];
    float rstd = stats[(b * NGROUP + g) * 2 + 1];
    float sc = rstd * gamma[tid];
    sArr[tid] = sc;
    tArr[tid] = beta[tid] - mean * sc;
  }
  for (int i = tid; i < 384; i += 256) biasS[i] = bias[i];
  __syncthreads();
  const float* xb = x + (size_t)b * NC * NPIX;
#pragma unroll
  for (int u = 0; u < 8; ++u) {
    int task = tid + u * 256;
    int p = task & 127, cc = task >> 7;
    int c0 = cc * 8;
    float v[8];
#pragma unroll
    for (int i = 0; i < 8; ++i)
      v[i] = sArr[c0 + i] * xb[(size_t)(c0 + i) * NPIX + p0 + p] + tArr[c0 + i];
    uint4 pk;
    pk.x = packbf(v[0], v[1]); pk.y = packbf(v[2], v[3]);
    pk.z = packbf(v[4], v[5]); pk.w = packbf(v[6], v[7]);
    *(uint4*)&Bt[((p << 4) + (cc ^ (p & 7))) << 3] = pk;
  }
  int lane = tid & 63, wv = tid >> 6;
  int lq = lane & 31, h = lane >> 5;

  for (int ot = 0; ot < 3; ++ot) {
    __syncthreads();  // At readers of previous iter done
#pragma unroll
    for (int u = 0; u < 8; ++u) {  // At <- wbuf tile ot, straight DMA
      int g = u * 4 + wv;          // chunk group 0..31
      __builtin_amdgcn_global_load_lds(
          (gvoid_t*)(wbuf + (((size_t)ot * 2048 + g * 64 + lane) << 3)),
          (svoid_t*)(At + (g << 9)), 16, 0, 0);
    }
    __syncthreads();  // drains vmcnt: At ready (Bt also visible on first iter)
    short8 af[8];
    int arow = wv * 32 + lq;
#pragma unroll
    for (int kk = 0; kk < 8; ++kk) {
      int ch = kk * 2 + h;
      af[kk] = *(const short8*)&At[((arow << 4) + (ch ^ (arow & 7))) << 3];
    }
#pragma unroll
    for (int np = 0; np < 2; ++np) {
      int nt0 = np * 2, nt1 = np * 2 + 1;
      int br0 = nt0 * 32 + lq, br1 = nt1 * 32 + lq;
      f32x16 a0, a1;
#pragma unroll
      for (int r = 0; r < 16; ++r) { a0[r] = 0.f; a1[r] = 0.f; }
      __builtin_amdgcn_s_setprio(1);
#pragma unroll
      for (int kk = 0; kk < 8; ++kk) {
        int ch = kk * 2 + h;
        short8 h0 = *(const short8*)&Bt[((br0 << 4) + (ch ^ (br0 & 7))) << 3];
        short8 h1 = *(const short8*)&Bt[((br1 << 4) + (ch ^ (br1 & 7))) << 3];
        a0 = __builtin_amdgcn_mfma_f32_32x32x16_bf16(af[kk], h0, a0, 0, 0, 0);
        a1 = __builtin_amdgcn_mfma_f32_32x32x16_bf16(af[kk], h1, a1, 0, 0, 0);
      }
      __builtin_amdgcn_s_setprio(0);
#pragma unroll
      for (int half = 0; half < 2; ++half) {
        f32x16& acc = half ? a1 : a0;
        int pg = p0 + (half ? nt1 : nt0) * 32 + lq;
        if (ot < 2) {  // Q or K: transposed bf16 store [p][c]
          ushort* dst = (ot == 0) ? qT : kT;
          float sc = (ot == 0) ? QSCALE : 1.0f;
#pragma unroll
          for (int g2 = 0; g2 < 4; ++g2) {
            int orow = wv * 32 + 4 * h + 8 * g2;
            uint2 st;
            st.x = packbf((acc[g2 * 4 + 0] + biasS[ot * 128 + orow + 0]) * sc,
                          (acc[g2 * 4 + 1] + biasS[ot * 128 + orow + 1]) * sc);
            st.y = packbf((acc[g2 * 4 + 2] + biasS[ot * 128 + orow + 2]) * sc,
                          (acc[g2 * 4 + 3] + biasS[ot * 128 + orow + 3]) * sc);
            *(uint2*)&dst[(((size_t)b << 12) + pg) * 128 + orow] = st;
          }
        } else {  // V: [c][n] bf16
#pragma unroll
          for (int r = 0; r < 16; ++r) {
            int orow = wv * 32 + (r & 3) + 8 * (r >> 2) + 4 * h;
            float vv = acc[r] + biasS[256 + orow];
            vB[((size_t)(b * 128 + orow) << 12) + pg] = bf16of(vv);
          }
        }
      }
    }
  }
}

// ---------------- K3: MFMA flash attention (4-chain QK, deferred sum) --------
__device__ __forceinline__ void attn_tile(const ushort* __restrict__ cur,
                                          const short8 (&qf)[8],
                                          f32x16 (&pacc)[4],
                                          float& m_run, float& l_run,
                                          int lq, int h, int swk) {
  // ---- QK^T (swapped): 4 independent MFMA chains of depth 4 ----
  f32x16 s0, s1, s0b, s1b;
#pragma unroll
  for (int r = 0; r < 16; ++r) { s0[r] = 0.f; s1[r] = 0.f; s0b[r] = 0.f; s1b[r] = 0.f; }
  __builtin_amdgcn_s_setprio(1);
#pragma unroll
  for (int kp = 0; kp < 4; ++kp) {
    int chA = (kp << 2) + h;       // kk=2kp   -> ch=4kp+h
    int chB = (kp << 2) + 2 + h;   // kk=2kp+1 -> ch=4kp+2+h
    short8 k0A = *(const short8*)&cur[(((lq) << 4) + (chA ^ swk)) << 3];
    short8 k1A = *(const short8*)&cur[(((32 + lq) << 4) + (chA ^ swk)) << 3];
    short8 k0B = *(const short8*)&cur[(((lq) << 4) + (chB ^ swk)) << 3];
    short8 k1B = *(const short8*)&cur[(((32 + lq) << 4) + (chB ^ swk)) << 3];
    s0  = __builtin_amdgcn_mfma_f32_32x32x16_bf16(k0A, qf[2 * kp],     s0,  0, 0, 0);
    s1  = __builtin_amdgcn_mfma_f32_32x32x16_bf16(k1A, qf[2 * kp],     s1,  0, 0, 0);
    s0b = __builtin_amdgcn_mfma_f32_32x32x16_bf16(k0B, qf[2 * kp + 1], s0b, 0, 0, 0);
    s1b = __builtin_amdgcn_mfma_f32_32x32x16_bf16(k1B, qf[2 * kp + 1], s1b, 0, 0, 0);
  }
  __builtin_amdgcn_s_setprio(0);
#pragma unroll
  for (int r = 0; r < 16; ++r) { s0[r] += s0b[r]; s1[r] += s1b[r]; }

  // ---- online softmax in exp2 domain, defer-max (THR=8) ----
  float tm[8];
#pragma unroll
  for (int r = 0; r < 8; ++r)
    tm[r] = fmaxf(fmaxf(s0[2 * r], s0[2 * r + 1]), fmaxf(s1[2 * r], s1[2 * r + 1]));
  float tmax = fmaxf(fmaxf(fmaxf(tm[0], tm[1]), fmaxf(tm[2], tm[3])),
                     fmaxf(fmaxf(tm[4], tm[5]), fmaxf(tm[6], tm[7])));
  tmax = fmaxf(tmax, __shfl_xor(tmax, 32));

  bool noresc = __all(tmax - m_run <= 8.f);  // P bounded by 2^8
  float mcur = noresc ? m_run : fmaxf(m_run, tmax);

#pragma unroll
  for (int r = 0; r < 16; ++r) { s0[r] = exp2f(s0[r] - mcur); }
#pragma unroll
  for (int r = 0; r < 16; ++r) { s1[r] = exp2f(s1[r] - mcur); }

  float alpha = 1.f;
  if (!noresc) {
    alpha = exp2f(m_run - mcur);
    m_run = mcur;
#pragma unroll
    for (int r = 0; r < 16; ++r) {
      int qr = (r & 3) + ((r >> 2) << 3) + (h << 2);
      float av = __shfl(alpha, qr);
      pacc[0][r] *= av; pacc[1][r] *= av; pacc[2][r] *= av; pacc[3][r] *= av;
    }
  }

  // ---- build PA fragments: A[q][j] for PV (P values in s0/s1) ----
  short8 pa[4];
#pragma unroll
  for (int kk = 0; kk < 4; ++kk) {
    float v0, v1, v2, v3, v4, v5, v6, v7;
    if (kk == 0)      { v0=s0[0];v1=s0[1];v2=s0[2];v3=s0[3];v4=s0[4];v5=s0[5];v6=s0[6];v7=s0[7]; }
    else if (kk == 1) { v0=s0[8];v1=s0[9];v2=s0[10];v3=s0[11];v4=s0[12];v5=s0[13];v6=s0[14];v7=s0[15]; }
    else if (kk == 2) { v0=s1[0];v1=s1[1];v2=s1[2];v3=s1[3];v4=s1[4];v5=s1[5];v6=s1[6];v7=s1[7]; }
    else              { v0=s1[8];v1=s1[9];v2=s1[10];v3=s1[11];v4=s1[12];v5=s1[13];v6=s1[14];v7=s1[15]; }
    unsigned P0a = packbf(v0, v1), P0b = packbf(v2, v3);
    unsigned P1a = packbf(v4, v5), P1b = packbf(v6, v7);
    unsigned sA = h ? P0a : P1a, sB = h ? P0b : P1b;
    unsigned rA = (unsigned)__shfl_xor((int)sA, 32);
    unsigned rB = (unsigned)__shfl_xor((int)sB, 32);
    uint4 wv;
    wv.x = h ? rA : P0a;  wv.y = h ? rB : P0b;
    wv.z = h ? P1a : rA;  wv.w = h ? P1b : rB;
    pa[kk] = __builtin_bit_cast(short8, wv);
  }

  // ---- PV: D[q][c] += P * V^T ----
  __builtin_amdgcn_s_setprio(1);
#pragma unroll
  for (int nt = 0; nt < 4; ++nt) {
    int row = (nt << 5) + lq;
#pragma unroll
    for (int kk = 0; kk < 4; ++kk) {
      int ch = (kk << 1) + h;
      short8 vf = *(const short8*)&cur[8192 + (((row << 3) + (ch ^ (lq & 7))) << 3)];
      pacc[nt] = __builtin_amdgcn_mfma_f32_32x32x16_bf16(pa[kk], vf, pacc[nt], 0, 0, 0);
    }
  }
  __builtin_amdgcn_s_setprio(0);

  // ---- deferred denominator: sum tree + l_run update (overlaps PV) ----
  float a0 = (s0[0] + s0[1]) + (s0[2] + s0[3]);
  float a1 = (s0[4] + s0[5]) + (s0[6] + s0[7]);
  float a2 = (s0[8] + s0[9]) + (s0[10] + s0[11]);
  float a3 = (s0[12] + s0[13]) + (s0[14] + s0[15]);
  float a4 = (s1[0] + s1[1]) + (s1[2] + s1[3]);
  float a5 = (s1[4] + s1[5]) + (s1[6] + s1[7]);
  float a6 = (s1[8] + s1[9]) + (s1[10] + s1[11]);
  float a7 = (s1[12] + s1[13]) + (s1[14] + s1[15]);
  float sum = ((a0 + a1) + (a2 + a3)) + ((a4 + a5) + (a6 + a7));
  sum += __shfl_xor(sum, 32);
  l_run = noresc ? (l_run + sum) : (l_run * alpha + sum);
}

__global__ __launch_bounds__(256, 2) void k_attn(const ushort* __restrict__ qT,
                                                 const ushort* __restrict__ kT,
                                                 const ushort* __restrict__ vB,
                                                 ushort* __restrict__ attP,
                                                 float2* __restrict__ mlv) {
  __shared__ ushort lds[32768];  // 2 x (K 16KB + V 16KB)
  int tid = threadIdx.x;
  int b = blockIdx.x, qt = blockIdx.y, s = blockIdx.z;  // b fastest -> XCD aff.
  int wid = tid >> 6;
  int lane = tid & 63;
  int lq = lane & 31;
  int h = lane >> 5;
  int swk = swK(lq);  // == swK(32+lq)
  int q0 = qt * 128 + wid * 32;
  int jbase = s * (NPIX / NSPLIT);

  short8 qf[8];
  const ushort* qp = qT + (((size_t)b << 12) + q0 + lq) * 128 + h * 8;
#pragma unroll
  for (int kk = 0; kk < 8; ++kk) qf[kk] = *(const short8*)(qp + kk * 16);

  f32x16 pacc[4];
#pragma unroll
  for (int nt = 0; nt < 4; ++nt)
#pragma unroll
    for (int r = 0; r < 16; ++r) pacc[nt][r] = 0.f;
  float m_run = -1e30f, l_run = 0.f;

  // ---- loop-invariant per-lane staging pointers ----
  int id0 = wid * 64 + lane;
  int krow0 = id0 >> 4, kch0 = id0 & 15;
  int vrow0 = id0 >> 3, vch0 = id0 & 7;
  const ushort* kbase = kT + (((size_t)b << 12) + jbase + krow0) * 128 +
                        ((kch0 ^ swK(krow0)) << 3);
  const ushort* vbase = vB + ((size_t)(b * 128 + vrow0) << 12) + jbase +
                        ((vch0 ^ (vrow0 & 7)) << 3);
  int tstage = 0;

#define STAGE(SEL)                                                              \
  do {                                                                          \
    if (tstage < JTILES) {                                                      \
      ushort* dbase = lds + (SEL) * 16384;                                      \
      _Pragma("unroll") for (int u = 0; u < 4; ++u) {                           \
        __builtin_amdgcn_global_load_lds((gvoid_t*)(kbase + u * 2048),          \
            (svoid_t*)(dbase + (u * 4 + wid) * 512), 16, 0, 0);                 \
        __builtin_amdgcn_global_load_lds((gvoid_t*)(vbase + u * 131072),        \
            (svoid_t*)(dbase + 8192 + (u * 4 + wid) * 512), 16, 0, 0);          \
      }                                                                         \
      kbase += 8192;  /* 64 keys * 128 c */                                     \
      vbase += 64;    /* 64 keys */                                             \
      ++tstage;                                                                 \
    }                                                                           \
  } while (0)

  STAGE(0);  // tile 0 -> buf0
  for (int it = 0; it < JTILES / 2; ++it) {
    __syncthreads();            // buf0 DMA done; prior buf0 readers done
    STAGE(1);                   // next tile -> buf1
    attn_tile(lds, qf, pacc, m_run, l_run, lq, h, swk);
    __syncthreads();            // buf1 DMA done; buf0 readers done
    STAGE(0);                   // next tile -> buf0
    attn_tile(lds + 16384, qf, pacc, m_run, l_run, lq, h, swk);
  }
#undef STAGE

  // ---- epilogue: bf16 partial O + (m,l); combine in k_proj ----
  size_t sb = (size_t)(s * NB + b);
#pragma unroll
  for (int r = 0; r < 16; ++r) {
    int qr = (r & 3) + ((r >> 2) << 3) + (h << 2);
    size_t rowbase = (((sb << 12) + q0 + qr) << 7) + lq;
    attP[rowbase]      = bf16of(pacc[0][r]);
    attP[rowbase + 32] = bf16of(pacc[1][r]);
    attP[rowbase + 64] = bf16of(pacc[2][r]);
    attP[rowbase + 96] = bf16of(pacc[3][r]);
  }
  if (h == 0) {
    mlv[(sb << 12) + q0 + lq] = make_float2(m_run, l_run);
  }
}

// ---------------- K4: split-combine (bf16) + proj (MFMA) + residual ----------
__global__ __launch_bounds__(256) void k_proj(const float* __restrict__ x,
                                              const ushort* __restrict__ attP,
                                              const float2* __restrict__ mlv,
                                              const ushort* __restrict__ wbuf,
                                              const float* __restrict__ bias,
                                              float* __restrict__ out) {
  __shared__ ushort At[128 * 128];
  __shared__ ushort Bt[128 * 128];
  __shared__ float c0s[128], c1s[128], biasS[128];
  int b = blockIdx.x, pt = blockIdx.y;  // b fastest
  int p0 = pt * 128;
  int tid = threadIdx.x;
  int lane = tid & 63, wv = tid >> 6;
  // At <- wbuf tile 3 (w_proj), straight DMA
#pragma unroll
  for (int u = 0; u < 8; ++u) {
    int g = u * 4 + wv;
    __builtin_amdgcn_global_load_lds(
        (gvoid_t*)(wbuf + (((size_t)3 * 2048 + g * 64 + lane) << 3)),
        (svoid_t*)(At + (g << 9)), 16, 0, 0);
  }
  if (tid < 128) {
    float2 ml0 = mlv[(((size_t)b) << 12) + p0 + tid];
    float2 ml1 = mlv[(((size_t)(NB + b)) << 12) + p0 + tid];
    float M = fmaxf(ml0.x, ml1.x);
    float e0 = exp2f(ml0.x - M), e1 = exp2f(ml1.x - M);
    float inv = 1.f / (ml0.y * e0 + ml1.y * e1);
    c0s[tid] = e0 * inv;
    c1s[tid] = e1 * inv;
    biasS[tid] = bias[tid];
  }
  __syncthreads();
#pragma unroll
  for (int u = 0; u < 8; ++u) {  // Bt: combine two bf16 splits -> bf16 swizzled
    int task = tid + u * 256;
    int p = task & 127, cc = task >> 7;
    const ushort* a0p = attP + ((((size_t)b << 12) + p0 + p) << 7) + cc * 8;
    const ushort* a1p = attP + ((((size_t)(NB + b) << 12) + p0 + p) << 7) + cc * 8;
    uint4 u0 = *(const uint4*)a0p;
    uint4 u1 = *(const uint4*)a1p;
    float c0 = c0s[p], c1 = c1s[p];
    uint4 pk;
    pk.x = packbf(bfl(u0.x) * c0 + bfl(u1.x) * c1,
                  bfh(u0.x) * c0 + bfh(u1.x) * c1);
    pk.y = packbf(bfl(u0.y) * c0 + bfl(u1.y) * c1,
                  bfh(u0.y) * c0 + bfh(u1.y) * c1);
    pk.z = packbf(bfl(u0.z) * c0 + bfl(u1.z) * c1,
                  bfh(u0.z) * c0 + bfh(u1.z) * c1);
    pk.w = packbf(bfl(u0.w) * c0 + bfl(u1.w) * c1,
                  bfh(u0.w) * c0 + bfh(u1.w) * c1);
    *(uint4*)&Bt[((p << 4) + (cc ^ (p & 7))) << 3] = pk;
  }
  __syncthreads();  // drains vmcnt (At DMA) + Bt ds_writes
  int lq = lane & 31, h = lane >> 5;
  short8 af[8];
  int arow = wv * 32 + lq;
#pragma unroll
  for (int kk = 0; kk < 8; ++kk) {
    int ch = kk * 2 + h;
    af[kk] = *(const short8*)&At[((arow << 4) + (ch ^ (arow & 7))) << 3];
  }
  const float* xb = x + (size_t)b * NC * NPIX;
  float* ob = out + (size_t)b * NC * NPIX;
#pragma unroll
  for (int np = 0; np < 2; ++np) {
    int nt0 = np * 2, nt1 = np * 2 + 1;
    int br0 = nt0 * 32 + lq, br1 = nt1 * 32 + lq;
    f32x16 a0, a1;
#pragma unroll
    for (int r = 0; r < 16; ++r) { a0[r] = 0.f; a1[r] = 0.f; }
    __builtin_amdgcn_s_setprio(1);
#pragma unroll
    for (int kk = 0; kk < 8; ++kk) {
      int ch = kk * 2 + h;
      short8 h0 = *(const short8*)&Bt[((br0 << 4) + (ch ^ (br0 & 7))) << 3];
      short8 h1 = *(const short8*)&Bt[((br1 << 4) + (ch ^ (br1 & 7))) << 3];
      a0 = __builtin_amdgcn_mfma_f32_32x32x16_bf16(af[kk], h0, a0, 0, 0, 0);
      a1 = __builtin_amdgcn_mfma_f32_32x32x16_bf16(af[kk], h1, a1, 0, 0, 0);
    }
    __builtin_amdgcn_s_setprio(0);
#pragma unroll
    for (int half = 0; half < 2; ++half) {
      f32x16& acc = half ? a1 : a0;
      int pg = p0 + (half ? nt1 : nt0) * 32 + lq;
#pragma unroll
      for (int r = 0; r < 16; ++r) {
        int orow = wv * 32 + (r & 3) + 8 * (r >> 2) + 4 * h;
        size_t idx = ((size_t)orow << 12) + pg;
        ob[idx] = acc[r] + biasS[orow] + xb[idx];
      }
    }
  }
}

extern "C" void kernel_launch(void* const* d_in, const int* in_sizes, int n_in,
                              void* d_out, int out_size, void* d_ws, size_t ws_size,
                              hipStream_t stream) {
  const float* x      = (const float*)d_in[0];
  const float* gamma  = (const float*)d_in[1];
  const float* beta   = (const float*)d_in[2];
  const float* w_qkv  = (const float*)d_in[3];
  const float* b_qkv  = (const float*)d_in[4];
  const float* w_proj = (const float*)d_in[5];
  const float* b_proj = (const float*)d_in[6];
  float* out = (float*)d_out;
  char* wsb = (char*)d_ws;

  float*  stats = (float*)wsb;                          // 1 KB
  ushort* qT    = (ushort*)(wsb + 1024);                // 8 MB
  ushort* kT    = (ushort*)(wsb + 1024 + (8u << 20));   // 8 MB
  ushort* vB    = (ushort*)(wsb + 1024 + (16u << 20));  // 8 MB
  ushort* attP  = (ushort*)(wsb + 1024 + (24u << 20));  // 16 MB (2 splits bf16)
  float2* mlv   = (float2*)(wsb + 1024 + (40u << 20));  // 512 KB
  ushort* wbuf  = (ushort*)(wsb + 1024 + (41u << 20));  // 128 KB

  hipLaunchKernelGGL(k_pre, dim3(96), dim3(256), 0, stream,
                     x, stats, w_qkv, w_proj, wbuf);
  hipLaunchKernelGGL(k_qkv, dim3(NB, NPIX / 128), dim3(256), 0, stream,
                     x, stats, gamma, beta, wbuf, b_qkv, qT, kT, vB);
  hipLaunchKernelGGL(k_attn, dim3(NB, NPIX / 128, NSPLIT), dim3(256), 0, stream,
                     qT, kT, vB, attP, mlv);
  hipLaunchKernelGGL(k_proj, dim3(NB, NPIX / 128), dim3(256), 0, stream,
                     x, attP, mlv, wbuf, b_proj, out);
}

// Round 14
// 134.274 us; speedup vs baseline: 1.0748x; 1.0354x over previous
//
#include <hip/hip_runtime.h>
#include <cstdint>

#define NB 8
#define NC 128
#define NPIX 4096
#define NGROUP 8
#define CPG 16
#define EPS_GN 1e-5f
// SCALE * log2(e): softmax done in exp2 domain
#define QSCALE 0.12751879523604132f
#define NSPLIT 2
#define JTILES (NPIX / 64 / NSPLIT)

typedef __attribute__((ext_vector_type(8))) short short8;
typedef __attribute__((ext_vector_type(16))) float f32x16;
typedef __attribute__((ext_vector_type(2))) int int2v;

typedef __attribute__((address_space(1))) const void gvoid_t;
typedef __attribute__((address_space(3))) void svoid_t;

// pack two f32 -> 2x bf16 (RNE) in one instruction (no builtin on gfx950)
__device__ __forceinline__ unsigned packbf(float lo, float hi) {
  unsigned r;
  asm("v_cvt_pk_bf16_f32 %0, %1, %2" : "=v"(r) : "v"(lo), "v"(hi));
  return r;
}
__device__ __forceinline__ ushort bf16of(float v) {
  return (ushort)(packbf(v, v) & 0xffffu);
}
__device__ __forceinline__ float bfl(unsigned w) {   // low bf16 -> f32
  return __builtin_bit_cast(float, w << 16);
}
__device__ __forceinline__ float bfh(unsigned w) {   // high bf16 -> f32
  return __builtin_bit_cast(float, w & 0xffff0000u);
}

// v_permlane32_swap_b32 with DISTINCT operands only (in-place swap semantics:
// vdst[32:63] <-> src0[0:31]). NEVER pass aliased values (r13 lesson).
__device__ __forceinline__ void plswap(unsigned& a, unsigned& b) {
  int2v r = __builtin_amdgcn_permlane32_swap((int)a, (int)b, false, false);
  a = (unsigned)r[0];
  b = (unsigned)r[1];
}

// K-tile chunk swizzle (16 chunks of 16B per 64-row): involution via XOR
__device__ __forceinline__ int swK(int row) {
  return ((row & 7) << 1) | ((row >> 3) & 1);
}

// ---------------- K1: fused prep: gn stats (blocks 0..63) + wprep (64..95) ---
__global__ __launch_bounds__(256) void k_pre(const float* __restrict__ x,
                                             float* __restrict__ stats,
                                             const float* __restrict__ wqkv,
                                             const float* __restrict__ wproj,
                                             ushort* __restrict__ wbuf) {
  int blk = blockIdx.x;
  if (blk < 64) {
    const float4* base = (const float4*)(x + (size_t)blk * CPG * NPIX);
    float s = 0.f, ss = 0.f;
    for (int i = threadIdx.x; i < CPG * NPIX / 4; i += 256) {
      float4 v = base[i];
      s  += v.x + v.y + v.z + v.w;
      ss += v.x * v.x + v.y * v.y + v.z * v.z + v.w * v.w;
    }
#pragma unroll
    for (int off = 32; off >= 1; off >>= 1) {
      s  += __shfl_down(s, off);
      ss += __shfl_down(ss, off);
    }
    __shared__ float red[8];
    int wid = threadIdx.x >> 6;
    if ((threadIdx.x & 63) == 0) { red[wid] = s; red[4 + wid] = ss; }
    __syncthreads();
    if (threadIdx.x == 0) {
      float S  = red[0] + red[1] + red[2] + red[3];
      float SS = red[4] + red[5] + red[6] + red[7];
      float mean = S * (1.f / (CPG * NPIX));
      float var  = SS * (1.f / (CPG * NPIX)) - mean * mean;
      stats[blk * 2]     = mean;
      stats[blk * 2 + 1] = rsqrtf(var + EPS_GN);
    }
  } else {
    int gi = (blk - 64) * 256 + threadIdx.x;  // 0..8191
    int t = gi >> 11, ci = gi & 2047;
    int o = ci >> 4, cc = (ci & 15) ^ (o & 7);
    const float* src = (t < 3) ? (wqkv + ((size_t)(t * 128 + o) * 128 + cc * 8))
                               : (wproj + ((size_t)o * 128 + cc * 8));
    float4 a = *(const float4*)src;
    float4 b2 = *(const float4*)(src + 4);
    uint4 pk;
    pk.x = packbf(a.x, a.y);  pk.y = packbf(a.z, a.w);
    pk.z = packbf(b2.x, b2.y); pk.w = packbf(b2.z, b2.w);
    *(uint4*)&wbuf[(size_t)gi << 3] = pk;
  }
}

// ---------------- K2: QKV GEMM (MFMA bf16), W tiles DMA'd from wbuf ----------
__global__ __launch_bounds__(256) void k_qkv(const float* __restrict__ x,
                                             const float* __restrict__ stats,
                                             const float* __restrict__ gamma,
                                             const float* __restrict__ beta,
                                             const ushort* __restrict__ wbuf,
                                             const float* __restrict__ bias,
                                             ushort* __restrict__ qT,
                                             ushort* __restrict__ kT,
                                             ushort* __restrict__ vB) {
  __shared__ ushort At[128 * 128];  // W o-tile, bf16, pre-swizzled via wbuf
  __shared__ ushort Bt[128 * 128];  // normalized x tile [p][c], bf16, swizzled
  __shared__ float sArr[128], tArr[128], biasS[384];
  int b = blockIdx.x, pt = blockIdx.y;  // b fastest -> XCD affinity
  int p0 = pt * 128;
  int tid = threadIdx.x;
  if (tid < 128) {
    int g = tid >> 4;
    float mean = stats[(b * NGROUP + g) * 2];
    float rstd = stats[(b * NGROUP + g) * 2 + 1];
    float sc = rstd * gamma[tid];
    sArr[tid] = sc;
    tArr[tid] = beta[tid] - mean * sc;
  }
  for (int i = tid; i < 384; i += 256) biasS[i] = bias[i];
  __syncthreads();
  const float* xb = x + (size_t)b * NC * NPIX;
#pragma unroll
  for (int u = 0; u < 8; ++u) {
    int task = tid + u * 256;
    int p = task & 127, cc = task >> 7;
    int c0 = cc * 8;
    float v[8];
#pragma unroll
    for (int i = 0; i < 8; ++i)
      v[i] = sArr[c0 + i] * xb[(size_t)(c0 + i) * NPIX + p0 + p] + tArr[c0 + i];
    uint4 pk;
    pk.x = packbf(v[0], v[1]); pk.y = packbf(v[2], v[3]);
    pk.z = packbf(v[4], v[5]); pk.w = packbf(v[6], v[7]);
    *(uint4*)&Bt[((p << 4) + (cc ^ (p & 7))) << 3] = pk;
  }
  int lane = tid & 63, wv = tid >> 6;
  int lq = lane & 31, h = lane >> 5;

  for (int ot = 0; ot < 3; ++ot) {
    __syncthreads();  // At readers of previous iter done
#pragma unroll
    for (int u = 0; u < 8; ++u) {  // At <- wbuf tile ot, straight DMA
      int g = u * 4 + wv;          // chunk group 0..31
      __builtin_amdgcn_global_load_lds(
          (gvoid_t*)(wbuf + (((size_t)ot * 2048 + g * 64 + lane) << 3)),
          (svoid_t*)(At + (g << 9)), 16, 0, 0);
    }
    __syncthreads();  // drains vmcnt: At ready (Bt also visible on first iter)
    short8 af[8];
    int arow = wv * 32 + lq;
#pragma unroll
    for (int kk = 0; kk < 8; ++kk) {
      int ch = kk * 2 + h;
      af[kk] = *(const short8*)&At[((arow << 4) + (ch ^ (arow & 7))) << 3];
    }
#pragma unroll
    for (int np = 0; np < 2; ++np) {
      int nt0 = np * 2, nt1 = np * 2 + 1;
      int br0 = nt0 * 32 + lq, br1 = nt1 * 32 + lq;
      f32x16 a0, a1;
#pragma unroll
      for (int r = 0; r < 16; ++r) { a0[r] = 0.f; a1[r] = 0.f; }
      __builtin_amdgcn_s_setprio(1);
#pragma unroll
      for (int kk = 0; kk < 8; ++kk) {
        int ch = kk * 2 + h;
        short8 h0 = *(const short8*)&Bt[((br0 << 4) + (ch ^ (br0 & 7))) << 3];
        short8 h1 = *(const short8*)&Bt[((br1 << 4) + (ch ^ (br1 & 7))) << 3];
        a0 = __builtin_amdgcn_mfma_f32_32x32x16_bf16(af[kk], h0, a0, 0, 0, 0);
        a1 = __builtin_amdgcn_mfma_f32_32x32x16_bf16(af[kk], h1, a1, 0, 0, 0);
      }
      __builtin_amdgcn_s_setprio(0);
#pragma unroll
      for (int half = 0; half < 2; ++half) {
        f32x16& acc = half ? a1 : a0;
        int pg = p0 + (half ? nt1 : nt0) * 32 + lq;
        if (ot < 2) {  // Q or K: transposed bf16 store [p][c]
          ushort* dst = (ot == 0) ? qT : kT;
          float sc = (ot == 0) ? QSCALE : 1.0f;
#pragma unroll
          for (int g2 = 0; g2 < 4; ++g2) {
            int orow = wv * 32 + 4 * h + 8 * g2;
            uint2 st;
            st.x = packbf((acc[g2 * 4 + 0] + biasS[ot * 128 + orow + 0]) * sc,
                          (acc[g2 * 4 + 1] + biasS[ot * 128 + orow + 1]) * sc);
            st.y = packbf((acc[g2 * 4 + 2] + biasS[ot * 128 + orow + 2]) * sc,
                          (acc[g2 * 4 + 3] + biasS[ot * 128 + orow + 3]) * sc);
            *(uint2*)&dst[(((size_t)b << 12) + pg) * 128 + orow] = st;
          }
        } else {  // V: [c][n] bf16
#pragma unroll
          for (int r = 0; r < 16; ++r) {
            int orow = wv * 32 + (r & 3) + 8 * (r >> 2) + 4 * h;
            float vv = acc[r] + biasS[256 + orow];
            vB[((size_t)(b * 128 + orow) << 12) + pg] = bf16of(vv);
          }
        }
      }
    }
  }
}

// ---------------- K3: MFMA flash attention --------------------------------
// shfl_xor reduces (verified r12) + permlane32_swap PA build (distinct regs).
__device__ __forceinline__ void attn_tile(const ushort* __restrict__ cur,
                                          const short8 (&qf)[8],
                                          f32x16 (&pacc)[4],
                                          float& m_run, float& l_run,
                                          int lq, int h, int swk) {
  // ---- QK^T (swapped): D[j][q] = K-tile * Q (2 chains) ----
  f32x16 s0, s1;
#pragma unroll
  for (int r = 0; r < 16; ++r) { s0[r] = 0.f; s1[r] = 0.f; }
  __builtin_amdgcn_s_setprio(1);
#pragma unroll
  for (int kk = 0; kk < 8; ++kk) {
    int ch = (kk << 1) + h;
    short8 kf0 = *(const short8*)&cur[(((lq) << 4) + (ch ^ swk)) << 3];
    short8 kf1 = *(const short8*)&cur[(((32 + lq) << 4) + (ch ^ swk)) << 3];
    s0 = __builtin_amdgcn_mfma_f32_32x32x16_bf16(kf0, qf[kk], s0, 0, 0, 0);
    s1 = __builtin_amdgcn_mfma_f32_32x32x16_bf16(kf1, qf[kk], s1, 0, 0, 0);
  }
  __builtin_amdgcn_s_setprio(0);

  // ---- online softmax in exp2 domain, defer-max (THR=8) ----
  float tm[8];
#pragma unroll
  for (int r = 0; r < 8; ++r)
    tm[r] = fmaxf(fmaxf(s0[2 * r], s0[2 * r + 1]), fmaxf(s1[2 * r], s1[2 * r + 1]));
  float tmax = fmaxf(fmaxf(fmaxf(tm[0], tm[1]), fmaxf(tm[2], tm[3])),
                     fmaxf(fmaxf(tm[4], tm[5]), fmaxf(tm[6], tm[7])));
  tmax = fmaxf(tmax, __shfl_xor(tmax, 32));

  bool noresc = __all(tmax - m_run <= 8.f);  // P bounded by 2^8
  float mcur = noresc ? m_run : fmaxf(m_run, tmax);

#pragma unroll
  for (int r = 0; r < 16; ++r) { s0[r] = exp2f(s0[r] - mcur); }
#pragma unroll
  for (int r = 0; r < 16; ++r) { s1[r] = exp2f(s1[r] - mcur); }

  float alpha = 1.f;
  if (!noresc) {
    alpha = exp2f(m_run - mcur);
    m_run = mcur;
#pragma unroll
    for (int r = 0; r < 16; ++r) {
      int qr = (r & 3) + ((r >> 2) << 3) + (h << 2);
      float av = __shfl(alpha, qr);
      pacc[0][r] *= av; pacc[1][r] *= av; pacc[2][r] *= av; pacc[3][r] *= av;
    }
  }

  // ---- build PA fragments via permlane32_swap (distinct operands) ----
  short8 pa[4];
#pragma unroll
  for (int kk = 0; kk < 4; ++kk) {
    float v0, v1, v2, v3, v4, v5, v6, v7;
    if (kk == 0)      { v0=s0[0];v1=s0[1];v2=s0[2];v3=s0[3];v4=s0[4];v5=s0[5];v6=s0[6];v7=s0[7]; }
    else if (kk == 1) { v0=s0[8];v1=s0[9];v2=s0[10];v3=s0[11];v4=s0[12];v5=s0[13];v6=s0[14];v7=s0[15]; }
    else if (kk == 2) { v0=s1[0];v1=s1[1];v2=s1[2];v3=s1[3];v4=s1[4];v5=s1[5];v6=s1[6];v7=s1[7]; }
    else              { v0=s1[8];v1=s1[9];v2=s1[10];v3=s1[11];v4=s1[12];v5=s1[13];v6=s1[14];v7=s1[15]; }
    unsigned P0a = packbf(v0, v1), P0b = packbf(v2, v3);
    unsigned P1a = packbf(v4, v5), P1b = packbf(v6, v7);
    plswap(P0a, P1a);  // P0a = [P0a.lo31|P1a.lo31] ; P1a = [P0a.hi31|P1a.hi31]
    plswap(P0b, P1b);
    uint4 wv;
    wv.x = P0a;  wv.y = P0b;
    wv.z = P1a;  wv.w = P1b;
    pa[kk] = __builtin_bit_cast(short8, wv);
  }

  // ---- PV: D[q][c] += P * V^T ----
  __builtin_amdgcn_s_setprio(1);
#pragma unroll
  for (int nt = 0; nt < 4; ++nt) {
    int row = (nt << 5) + lq;
#pragma unroll
    for (int kk = 0; kk < 4; ++kk) {
      int ch = (kk << 1) + h;
      short8 vf = *(const short8*)&cur[8192 + (((row << 3) + (ch ^ (lq & 7))) << 3)];
      pacc[nt] = __builtin_amdgcn_mfma_f32_32x32x16_bf16(pa[kk], vf, pacc[nt], 0, 0, 0);
    }
  }
  __builtin_amdgcn_s_setprio(0);

  // ---- deferred denominator: sum tree + shfl cross-half (verified path) ----
  float a0 = (s0[0] + s0[1]) + (s0[2] + s0[3]);
  float a1 = (s0[4] + s0[5]) + (s0[6] + s0[7]);
  float a2 = (s0[8] + s0[9]) + (s0[10] + s0[11]);
  float a3 = (s0[12] + s0[13]) + (s0[14] + s0[15]);
  float a4 = (s1[0] + s1[1]) + (s1[2] + s1[3]);
  float a5 = (s1[4] + s1[5]) + (s1[6] + s1[7]);
  float a6 = (s1[8] + s1[9]) + (s1[10] + s1[11]);
  float a7 = (s1[12] + s1[13]) + (s1[14] + s1[15]);
  float sum = ((a0 + a1) + (a2 + a3)) + ((a4 + a5) + (a6 + a7));
  sum += __shfl_xor(sum, 32);
  l_run = noresc ? (l_run + sum) : (l_run * alpha + sum);
}

__global__ __launch_bounds__(256, 2) void k_attn(const ushort* __restrict__ qT,
                                                 const ushort* __restrict__ kT,
                                                 const ushort* __restrict__ vB,
                                                 ushort* __restrict__ attP,
                                                 float2* __restrict__ mlv) {
  __shared__ ushort lds[32768];  // 2 x (K 16KB + V 16KB)
  int tid = threadIdx.x;
  int b = blockIdx.x, qt = blockIdx.y, s = blockIdx.z;  // b fastest -> XCD aff.
  int wid = tid >> 6;
  int lane = tid & 63;
  int lq = lane & 31;
  int h = lane >> 5;
  int swk = swK(lq);  // == swK(32+lq)
  int q0 = qt * 128 + wid * 32;
  int jbase = s * (NPIX / NSPLIT);

  short8 qf[8];
  const ushort* qp = qT + (((size_t)b << 12) + q0 + lq) * 128 + h * 8;
#pragma unroll
  for (int kk = 0; kk < 8; ++kk) qf[kk] = *(const short8*)(qp + kk * 16);

  f32x16 pacc[4];
#pragma unroll
  for (int nt = 0; nt < 4; ++nt)
#pragma unroll
    for (int r = 0; r < 16; ++r) pacc[nt][r] = 0.f;
  float m_run = -1e30f, l_run = 0.f;

  // ---- loop-invariant per-lane staging pointers ----
  int id0 = wid * 64 + lane;
  int krow0 = id0 >> 4, kch0 = id0 & 15;
  int vrow0 = id0 >> 3, vch0 = id0 & 7;
  const ushort* kbase = kT + (((size_t)b << 12) + jbase + krow0) * 128 +
                        ((kch0 ^ swK(krow0)) << 3);
  const ushort* vbase = vB + ((size_t)(b * 128 + vrow0) << 12) + jbase +
                        ((vch0 ^ (vrow0 & 7)) << 3);
  int tstage = 0;

#define STAGE(SEL)                                                              \
  do {                                                                          \
    if (tstage < JTILES) {                                                      \
      ushort* dbase = lds + (SEL) * 16384;                                      \
      _Pragma("unroll") for (int u = 0; u < 4; ++u) {                           \
        __builtin_amdgcn_global_load_lds((gvoid_t*)(kbase + u * 2048),          \
            (svoid_t*)(dbase + (u * 4 + wid) * 512), 16, 0, 0);                 \
        __builtin_amdgcn_global_load_lds((gvoid_t*)(vbase + u * 131072),        \
            (svoid_t*)(dbase + 8192 + (u * 4 + wid) * 512), 16, 0, 0);          \
      }                                                                         \
      kbase += 8192;  /* 64 keys * 128 c */                                     \
      vbase += 64;    /* 64 keys */                                             \
      ++tstage;                                                                 \
    }                                                                           \
  } while (0)

  STAGE(0);  // tile 0 -> buf0
  for (int it = 0; it < JTILES / 2; ++it) {
    __syncthreads();            // buf0 DMA done; prior buf0 readers done
    STAGE(1);                   // next tile -> buf1
    attn_tile(lds, qf, pacc, m_run, l_run, lq, h, swk);
    __syncthreads();            // buf1 DMA done; buf0 readers done
    STAGE(0);                   // next tile -> buf0
    attn_tile(lds + 16384, qf, pacc, m_run, l_run, lq, h, swk);
  }
#undef STAGE

  // ---- epilogue: bf16 partial O + (m,l); combine in k_proj ----
  size_t sb = (size_t)(s * NB + b);
#pragma unroll
  for (int r = 0; r < 16; ++r) {
    int qr = (r & 3) + ((r >> 2) << 3) + (h << 2);
    size_t rowbase = (((sb << 12) + q0 + qr) << 7) + lq;
    attP[rowbase]      = bf16of(pacc[0][r]);
    attP[rowbase + 32] = bf16of(pacc[1][r]);
    attP[rowbase + 64] = bf16of(pacc[2][r]);
    attP[rowbase + 96] = bf16of(pacc[3][r]);
  }
  if (h == 0) {
    mlv[(sb << 12) + q0 + lq] = make_float2(m_run, l_run);
  }
}

// ---------------- K4: split-combine (bf16) + proj (MFMA) + residual ----------
__global__ __launch_bounds__(256) void k_proj(const float* __restrict__ x,
                                              const ushort* __restrict__ attP,
                                              const float2* __restrict__ mlv,
                                              const ushort* __restrict__ wbuf,
                                              const float* __restrict__ bias,
                                              float* __restrict__ out) {
  __shared__ ushort At[128 * 128];
  __shared__ ushort Bt[128 * 128];
  __shared__ float c0s[128], c1s[128], biasS[128];
  int b = blockIdx.x, pt = blockIdx.y;  // b fastest
  int p0 = pt * 128;
  int tid = threadIdx.x;
  int lane = tid & 63, wv = tid >> 6;
  // At <- wbuf tile 3 (w_proj), straight DMA
#pragma unroll
  for (int u = 0; u < 8; ++u) {
    int g = u * 4 + wv;
    __builtin_amdgcn_global_load_lds(
        (gvoid_t*)(wbuf + (((size_t)3 * 2048 + g * 64 + lane) << 3)),
        (svoid_t*)(At + (g << 9)), 16, 0, 0);
  }
  if (tid < 128) {
    float2 ml0 = mlv[(((size_t)b) << 12) + p0 + tid];
    float2 ml1 = mlv[(((size_t)(NB + b)) << 12) + p0 + tid];
    float M = fmaxf(ml0.x, ml1.x);
    float e0 = exp2f(ml0.x - M), e1 = exp2f(ml1.x - M);
    float inv = 1.f / (ml0.y * e0 + ml1.y * e1);
    c0s[tid] = e0 * inv;
    c1s[tid] = e1 * inv;
    biasS[tid] = bias[tid];
  }
  __syncthreads();
#pragma unroll
  for (int u = 0; u < 8; ++u) {  // Bt: combine two bf16 splits -> bf16 swizzled
    int task = tid + u * 256;
    int p = task & 127, cc = task >> 7;
    const ushort* a0p = attP + ((((size_t)b << 12) + p0 + p) << 7) + cc * 8;
    const ushort* a1p = attP + ((((size_t)(NB + b) << 12) + p0 + p) << 7) + cc * 8;
    uint4 u0 = *(const uint4*)a0p;
    uint4 u1 = *(const uint4*)a1p;
    float c0 = c0s[p], c1 = c1s[p];
    uint4 pk;
    pk.x = packbf(bfl(u0.x) * c0 + bfl(u1.x) * c1,
                  bfh(u0.x) * c0 + bfh(u1.x) * c1);
    pk.y = packbf(bfl(u0.y) * c0 + bfl(u1.y) * c1,
                  bfh(u0.y) * c0 + bfh(u1.y) * c1);
    pk.z = packbf(bfl(u0.z) * c0 + bfl(u1.z) * c1,
                  bfh(u0.z) * c0 + bfh(u1.z) * c1);
    pk.w = packbf(bfl(u0.w) * c0 + bfl(u1.w) * c1,
                  bfh(u0.w) * c0 + bfh(u1.w) * c1);
    *(uint4*)&Bt[((p << 4) + (cc ^ (p & 7))) << 3] = pk;
  }
  __syncthreads();  // drains vmcnt (At DMA) + Bt ds_writes
  int lq = lane & 31, h = lane >> 5;
  short8 af[8];
  int arow = wv * 32 + lq;
#pragma unroll
  for (int kk = 0; kk < 8; ++kk) {
    int ch = kk * 2 + h;
    af[kk] = *(const short8*)&At[((arow << 4) + (ch ^ (arow & 7))) << 3];
  }
  const float* xb = x + (size_t)b * NC * NPIX;
  float* ob = out + (size_t)b * NC * NPIX;
#pragma unroll
  for (int np = 0; np < 2; ++np) {
    int nt0 = np * 2, nt1 = np * 2 + 1;
    int br0 = nt0 * 32 + lq, br1 = nt1 * 32 + lq;
    f32x16 a0, a1;
#pragma unroll
    for (int r = 0; r < 16; ++r) { a0[r] = 0.f; a1[r] = 0.f; }
    __builtin_amdgcn_s_setprio(1);
#pragma unroll
    for (int kk = 0; kk < 8; ++kk) {
      int ch = kk * 2 + h;
      short8 h0 = *(const short8*)&Bt[((br0 << 4) + (ch ^ (br0 & 7))) << 3];
      short8 h1 = *(const short8*)&Bt[((br1 << 4) + (ch ^ (br1 & 7))) << 3];
      a0 = __builtin_amdgcn_mfma_f32_32x32x16_bf16(af[kk], h0, a0, 0, 0, 0);
      a1 = __builtin_amdgcn_mfma_f32_32x32x16_bf16(af[kk], h1, a1, 0, 0, 0);
    }
    __builtin_amdgcn_s_setprio(0);
#pragma unroll
    for (int half = 0; half < 2; ++half) {
      f32x16& acc = half ? a1 : a0;
      int pg = p0 + (half ? nt1 : nt0) * 32 + lq;
#pragma unroll
      for (int r = 0; r < 16; ++r) {
        int orow = wv * 32 + (r & 3) + 8 * (r >> 2) + 4 * h;
        size_t idx = ((size_t)orow << 12) + pg;
        ob[idx] = acc[r] + biasS[orow] + xb[idx];
      }
    }
  }
}

extern "C" void kernel_launch(void* const* d_in, const int* in_sizes, int n_in,
                              void* d_out, int out_size, void* d_ws, size_t ws_size,
                              hipStream_t stream) {
  const float* x      = (const float*)d_in[0];
  const float* gamma  = (const float*)d_in[1];
  const float* beta   = (const float*)d_in[2];
  const float* w_qkv  = (const float*)d_in[3];
  const float* b_qkv  = (const float*)d_in[4];
  const float* w_proj = (const float*)d_in[5];
  const float* b_proj = (const float*)d_in[6];
  float* out = (float*)d_out;
  char* wsb = (char*)d_ws;

  float*  stats = (float*)wsb;                          // 1 KB
  ushort* qT    = (ushort*)(wsb + 1024);                // 8 MB
  ushort* kT    = (ushort*)(wsb + 1024 + (8u << 20));   // 8 MB
  ushort* vB    = (ushort*)(wsb + 1024 + (16u << 20));  // 8 MB
  ushort* attP  = (ushort*)(wsb + 1024 + (24u << 20));  // 16 MB (2 splits bf16)
  float2* mlv   = (float2*)(wsb + 1024 + (40u << 20));  // 512 KB
  ushort* wbuf  = (ushort*)(wsb + 1024 + (41u << 20));  // 128 KB

  hipLaunchKernelGGL(k_pre, dim3(96), dim3(256), 0, stream,
                     x, stats, w_qkv, w_proj, wbuf);
  hipLaunchKernelGGL(k_qkv, dim3(NB, NPIX / 128), dim3(256), 0, stream,
                     x, stats, gamma, beta, wbuf, b_qkv, qT, kT, vB);
  hipLaunchKernelGGL(k_attn, dim3(NB, NPIX / 128, NSPLIT), dim3(256), 0, stream,
                     qT, kT, vB, attP, mlv);
  hipLaunchKernelGGL(k_proj, dim3(NB, NPIX / 128), dim3(256), 0, stream,
                     x, attP, mlv, wbuf, b_proj, out);
}